// Round 8
// baseline (297.006 us; speedup 1.0000x reference)
//
#include <hip/hip_runtime.h>
#include <stdint.h>

#define NTOK 8192
#define DIM 1024
#define EDIM 2048

typedef __attribute__((ext_vector_type(8))) short bf16x8;
typedef __attribute__((ext_vector_type(4))) float f32x4;

__device__ __forceinline__ unsigned short f2bf(float f) {
  union { float f; unsigned u; } v; v.f = f;
  unsigned r = (v.u + 0x7FFF + ((v.u >> 16) & 1)) >> 16;
  return (unsigned short)r;
}

__device__ __forceinline__ unsigned pack2bf(float a, float b) {
  return (unsigned)f2bf(a) | ((unsigned)f2bf(b) << 16);
}

__device__ __forceinline__ void gload16(const void* g, void* l) {
  __builtin_amdgcn_global_load_lds(
      (const __attribute__((address_space(1))) unsigned int*)g,
      (__attribute__((address_space(3))) unsigned int*)l, 16, 0, 0);
}

// ---- mega preproc: blocks [0,1024) = x->bf16 + router logits;
// ---- blocks [1024, 1024+9*512) = 64x64 weight transpose/cast tiles ---------
__global__ void pre_k(const float* __restrict__ x, const float* __restrict__ Wr,
                      const float* __restrict__ bias,
                      const float* __restrict__ Sg, const float* __restrict__ Su,
                      const float* __restrict__ Sd, const float* __restrict__ Wg,
                      const float* __restrict__ Wu, const float* __restrict__ Wd,
                      unsigned short* __restrict__ xb, int* __restrict__ choice,
                      unsigned short* __restrict__ wt) {
  const int bx = blockIdx.x;
  const int t = threadIdx.x;
  const size_t MSZ = (size_t)DIM * EDIM;
  if (bx < 1024) {
    const int wid = t >> 6, lane = t & 63;
    const float b0 = bias[0], b1 = bias[1];
    const float2* wr = (const float2*)Wr;
    #pragma unroll
    for (int r = 0; r < 2; ++r) {
      const int n = bx * 8 + wid * 2 + r;
      const float4* xr = (const float4*)(x + (size_t)n * DIM);
      uint2* xo = (uint2*)(xb + (size_t)n * DIM);
      float s0 = 0.f, s1 = 0.f;
      #pragma unroll
      for (int i = 0; i < 4; ++i) {
        const int idx = i * 64 + lane;
        float4 v = xr[idx];
        float2 wa = wr[idx * 4], wb = wr[idx * 4 + 1], wc = wr[idx * 4 + 2], wd = wr[idx * 4 + 3];
        s0 += v.x * wa.x + v.y * wb.x + v.z * wc.x + v.w * wd.x;
        s1 += v.x * wa.y + v.y * wb.y + v.z * wc.y + v.w * wd.y;
        union { unsigned short s[4]; uint2 u; } o;
        o.s[0] = f2bf(v.x); o.s[1] = f2bf(v.y); o.s[2] = f2bf(v.z); o.s[3] = f2bf(v.w);
        xo[idx] = o.u;
      }
      #pragma unroll
      for (int off = 32; off; off >>= 1) {
        s0 += __shfl_xor(s0, off);
        s1 += __shfl_xor(s1, off);
      }
      if (lane == 0) choice[n] = (s1 + b1 > s0 + b0) ? 1 : 0;
    }
    return;
  }
  // ---- 64x64 transpose tiles; gate/up interleave 16-wide:
  // ---- f -> row (f>>4)*32 + (f&15) + type*16
  const int id = bx - 1024;
  const int mat = id >> 9;           // 512 tiles per matrix
  const int tile = id & 511;
  const float* src; unsigned short* dst; int type;
  switch (mat) {
    case 0: src = Sg;       dst = wt;            type = 0; break;
    case 1: src = Su;       dst = wt;            type = 1; break;
    case 2: src = Wg;       dst = wt + 4194304;  type = 0; break;
    case 3: src = Wu;       dst = wt + 4194304;  type = 1; break;
    case 4: src = Wg + MSZ; dst = wt + 8388608;  type = 0; break;
    case 5: src = Wu + MSZ; dst = wt + 8388608;  type = 1; break;
    case 6: src = Sd;       dst = wt + 12582912; type = 2; break;
    case 7: src = Wd;       dst = wt + 14680064; type = 2; break;
    default: src = Wd + MSZ; dst = wt + 16777216; type = 2; break;
  }
  const int C = (type == 2) ? DIM : EDIM;       // src cols (output N index)
  const int OSTR = (type == 2) ? EDIM : DIM;    // dst row stride
  __shared__ float ts[64][65];
  const int tC = C >> 6;
  const int r0 = (tile / tC) * 64, c0 = (tile % tC) * 64;
  {
    const int row4 = t >> 4, col4 = (t & 15) * 4;
    #pragma unroll
    for (int p = 0; p < 4; ++p) {
      const int row = p * 16 + row4;
      const float4 v = *(const float4*)&src[(size_t)(r0 + row) * C + c0 + col4];
      ts[row][col4 + 0] = v.x; ts[row][col4 + 1] = v.y;
      ts[row][col4 + 2] = v.z; ts[row][col4 + 3] = v.w;
    }
  }
  __syncthreads();
  {
    const int ch = t & 7;
    #pragma unroll
    for (int q = 0; q < 2; ++q) {
      const int fl = q * 32 + (t >> 3);
      float v0 = ts[ch * 8 + 0][fl], v1 = ts[ch * 8 + 1][fl];
      float v2 = ts[ch * 8 + 2][fl], v3 = ts[ch * 8 + 3][fl];
      float v4 = ts[ch * 8 + 4][fl], v5 = ts[ch * 8 + 5][fl];
      float v6 = ts[ch * 8 + 6][fl], v7 = ts[ch * 8 + 7][fl];
      uint4 o;
      o.x = pack2bf(v0, v1); o.y = pack2bf(v2, v3);
      o.z = pack2bf(v4, v5); o.w = pack2bf(v6, v7);
      const int f = c0 + fl;
      const int orow = (type == 2) ? f : (((f >> 4) << 5) + (f & 15) + (type << 4));
      *(uint4*)&dst[(size_t)orow * OSTR + r0 + ch * 8] = o;
    }
  }
}

// ---- single-block prefix scan -> compacted expert-sorted rowlist ------------
__global__ void scan_k(const int* __restrict__ choice, int* __restrict__ counts,
                       int* __restrict__ rowlist) {
  const int t = threadIdx.x;
  const int base = t * 8;
  int c[8]; int ones = 0;
  #pragma unroll
  for (int j = 0; j < 8; ++j) { c[j] = choice[base + j]; ones += c[j]; }
  const int lane = t & 63, wid = t >> 6;
  int v = ones;
  #pragma unroll
  for (int off = 1; off < 64; off <<= 1) {
    int o = __shfl_up(v, off);
    if (lane >= off) v += o;
  }
  __shared__ int wsum[16];
  if (lane == 63) wsum[wid] = v;
  __syncthreads();
  int pre = 0, tot = 0;
  #pragma unroll
  for (int w = 0; w < 16; ++w) {
    int s = wsum[w];
    if (w < wid) pre += s;
    tot += s;
  }
  const int excl = pre + v - ones;
  const int cnt0 = NTOK - tot;
  int p0 = base - excl;
  int p1 = cnt0 + excl;
  #pragma unroll
  for (int j = 0; j < 8; ++j) {
    if (c[j]) rowlist[p1++] = base + j;
    else rowlist[p0++] = base + j;
  }
  if (t == 0) { counts[0] = cnt0; counts[1] = tot; }
}

// ---- dual-m-tile 256x128 MFMA GEMM: 512 thr (8 waves), 48KB LDS, 3/CU cap ---
// Two 128-row m-tiles share one B panel (B L2-fill traffic halves; 6 gloads/
// thread/K-step vs 8). Inner loop / swizzle / epilogues identical to the
// proven 128x128 kernel; wave wid>>2 selects the A half (mhalf).
// MODE 0: up shared   (A=xb linear,  B=Bsh=Sgu,    h_s[pos] = silu(g)*u)
// MODE 1: up routed   (A=xb gather,  B=Brt+e*4M,   h_r[mstart+pos] = silu*u)
// MODE 2: down shared (A=h_s linear, B=Bsh=Sdt,    out[row] = )
// MODE 3: down routed (A=h_r compact,B=Brt+e*2M,   out[rl[row]] += scatter)
// MODE 4: merged up   (bx<32 -> shared job, else routed job; needs h_s != h_r)
template<int KDIM, int MODE>
__global__ __launch_bounds__(512, 4)
void gemm3_k(const unsigned short* __restrict__ A, const unsigned short* __restrict__ Bsh,
             const unsigned short* __restrict__ Brt, const int* __restrict__ counts,
             const int* __restrict__ rl, unsigned short* __restrict__ h_s,
             unsigned short* __restrict__ h_r, float* __restrict__ out) {
  constexpr int NT = KDIM / 64;
  constexpr int ROWB = KDIM * 2;

  int e = 0, mstart = 0, cntE = NTOK, r0;
  bool gat = false;
  const unsigned short* B;
  if (MODE == 4) {
    const int mt = blockIdx.x;
    if (mt < 32) { r0 = mt * 256; B = Bsh; }
    else {
      const int m2 = mt - 32;
      e = m2 >> 5;
      const int tile = m2 & 31;
      const int c0 = counts[0];
      cntE = e ? (NTOK - c0) : c0;
      mstart = e ? c0 : 0;
      r0 = tile * 256;
      if (r0 >= cntE) return;
      B = Brt + (size_t)e * 4194304u;
      gat = true;
    }
  } else if (MODE == 0) { r0 = blockIdx.x * 256; B = Bsh; }
  else if (MODE == 1) {
    e = blockIdx.x >> 5;
    const int tile = blockIdx.x & 31;
    const int c0 = counts[0];
    cntE = e ? (NTOK - c0) : c0;
    mstart = e ? c0 : 0;
    r0 = tile * 256;
    if (r0 >= cntE) return;
    B = Brt + (size_t)e * 4194304u;
    gat = true;
  } else if (MODE == 2) { r0 = blockIdx.x * 256; B = Bsh; }
  else {  // MODE 3
    e = blockIdx.x >> 5;
    const int tile = blockIdx.x & 31;
    const int c0 = counts[0];
    cntE = e ? (NTOK - c0) : c0;
    mstart = e ? c0 : 0;
    r0 = tile * 256;
    if (r0 >= cntE) return;
    B = Brt + (size_t)e * 2097152u;
  }
  const int n0 = blockIdx.y * 128;

  __shared__ __align__(16) unsigned char lA[32768];   // 256 rows x 128 B
  __shared__ __align__(16) unsigned char lB[16384];   // 128 rows x 128 B

  const int t = threadIdx.x;
  const int lane = t & 63;
  const int wid = t >> 6;
  const int mhalf = wid >> 2;                 // which 128-row m-tile
  const int wm = (wid >> 1) & 1, wn = wid & 1;
  const int l15 = lane & 15, l4 = lane >> 4;

  size_t aoff[4]; uint32_t boff[2]; int dstoA[4], dstoB[2];
  #pragma unroll
  for (int i = 0; i < 4; ++i) {
    const int flat = i * 8192 + t * 16;
    const int row = flat >> 7;                // 0..255
    const int kb = (flat & 127) ^ ((row & 7) << 4);
    int idx = r0 + row;
    int ar;
    if (MODE == 1 || MODE == 4) {
      if (gat) { if (idx >= cntE) idx = cntE - 1; ar = rl[mstart + idx]; }
      else ar = idx;
    } else if (MODE == 3) {
      if (idx >= cntE) idx = cntE - 1;
      ar = mstart + idx;
    } else ar = idx;
    aoff[i] = (size_t)ar * ROWB + kb;
    dstoA[i] = flat;
  }
  #pragma unroll
  for (int i = 0; i < 2; ++i) {
    const int flat = i * 8192 + t * 16;
    const int row = flat >> 7;                // 0..127
    const int kb = (flat & 127) ^ ((row & 7) << 4);
    boff[i] = (uint32_t)(n0 + row) * ROWB + kb;
    dstoB[i] = flat;
  }

  f32x4 acc[4][4];
  #pragma unroll
  for (int i = 0; i < 4; ++i)
    #pragma unroll
    for (int j = 0; j < 4; ++j) acc[i][j] = f32x4{0.f, 0.f, 0.f, 0.f};

  const char* Ab = (const char*)A;
  const char* Bb = (const char*)B;

  for (int kt = 0; kt < NT; ++kt) {
    __syncthreads();
    const size_t ko = (size_t)kt * 128;
    #pragma unroll
    for (int i = 0; i < 4; ++i)
      gload16(Ab + aoff[i] + ko, lA + dstoA[i]);
    #pragma unroll
    for (int i = 0; i < 2; ++i)
      gload16(Bb + boff[i] + ko, lB + dstoB[i]);
    __syncthreads();
    #pragma unroll
    for (int ks = 0; ks < 2; ++ks) {
      bf16x8 af[4], bf[4];
      const int kb = ks * 64 + (l4 << 4);
      #pragma unroll
      for (int mi = 0; mi < 4; ++mi) {
        const int row = mhalf * 128 + wm * 64 + mi * 16 + l15;
        af[mi] = *(const bf16x8*)(lA + row * 128 + (kb ^ ((row & 7) << 4)));
      }
      #pragma unroll
      for (int ni = 0; ni < 4; ++ni) {
        const int col = wn * 64 + ni * 16 + l15;
        bf[ni] = *(const bf16x8*)(lB + col * 128 + (kb ^ ((col & 7) << 4)));
      }
      #pragma unroll
      for (int mi = 0; mi < 4; ++mi)
        #pragma unroll
        for (int ni = 0; ni < 4; ++ni)
          acc[mi][ni] = __builtin_amdgcn_mfma_f32_16x16x32_bf16(af[mi], bf[ni], acc[mi][ni], 0, 0, 0);
    }
  }

  // epilogue
  #pragma unroll
  for (int mi = 0; mi < 4; ++mi) {
    #pragma unroll
    for (int r = 0; r < 4; ++r) {
      const int rit = mhalf * 128 + wm * 64 + mi * 16 + l4 * 4 + r;
      const int pos = r0 + rit;
      if (MODE == 0 || MODE == 1 || MODE == 4) {
        if (gat && pos >= cntE) continue;
        unsigned short* hr = (gat ? h_r : h_s) + (size_t)(mstart + pos) * EDIM;
        const int f0 = (n0 >> 1) + wn * 32;
        #pragma unroll
        for (int j = 0; j < 2; ++j) {
          const float g = acc[mi][2 * j][r], u = acc[mi][2 * j + 1][r];
          hr[f0 + j * 16 + l15] = f2bf(g / (1.f + __expf(-g)) * u);
        }
      } else if (MODE == 2) {
        float* orow = out + (size_t)pos * DIM;
        #pragma unroll
        for (int n = 0; n < 4; ++n)
          orow[n0 + wn * 64 + n * 16 + l15] = acc[mi][n][r];
      } else {
        if (pos >= cntE) continue;
        const int tok = rl[mstart + pos];
        float* orow = out + (size_t)tok * DIM;
        #pragma unroll
        for (int n = 0; n < 4; ++n)
          orow[n0 + wn * 64 + n * 16 + l15] += acc[mi][n][r];
      }
    }
  }
}

extern "C" void kernel_launch(void* const* d_in, const int* in_sizes, int n_in,
                              void* d_out, int out_size, void* d_ws, size_t ws_size,
                              hipStream_t stream) {
  const float* x  = (const float*)d_in[0];
  const float* Wr = (const float*)d_in[1];
  const float* rb = (const float*)d_in[2];
  const float* Wg = (const float*)d_in[3];
  const float* Wu = (const float*)d_in[4];
  const float* Wd = (const float*)d_in[5];
  const float* Sg = (const float*)d_in[6];
  const float* Su = (const float*)d_in[7];
  const float* Sd = (const float*)d_in[8];
  float* out = (float*)d_out;

  char* ws = (char*)d_ws;
  int* counts  = (int*)ws;                                 // 256 B
  int* choice  = (int*)(ws + 256);                         // 32 KiB
  int* rowlist = (int*)(ws + 256 + 32768);                 // 32 KiB
  unsigned short* xb = (unsigned short*)(ws + 256 + 65536);  // 16 MiB
  unsigned short* wt = xb + (size_t)NTOK * DIM;            // 36 MiB of weights
  unsigned short* h1 = wt + 18874368;                      // [8192][2048] bf16
  unsigned short* h2 = h1 + (size_t)NTOK * EDIM;           // second h (merged path)

  const unsigned short* Sgu  = wt;             // [4096][1024] gate/up interleaved
  const unsigned short* Wgu0 = wt + 4194304;   // 2 x [4096][1024]
  const unsigned short* Sdt  = wt + 12582912;  // [1024][2048]
  const unsigned short* Wdt0 = wt + 14680064;  // 2 x [1024][2048]

  pre_k<<<1024 + 9 * 512, 256, 0, stream>>>(x, Wr, rb, Sg, Su, Sd, Wg, Wu, Wd,
                                            xb, choice, wt);
  scan_k<<<1, 1024, 0, stream>>>(choice, counts, rowlist);

  const size_t needed = 256 + 65536 + 16777216ull + 37748736ull + 2 * 33554432ull;
  if (ws_size >= needed) {
    // merged ups (shared job: bx<32; routed job: bx in [32,96)) -> h1 / h2
    gemm3_k<DIM, 4><<<dim3(96, 32), 512, 0, stream>>>(xb, Sgu, Wgu0, counts, rowlist, h1, h2, nullptr);
    gemm3_k<EDIM, 2><<<dim3(32, 8), 512, 0, stream>>>(h1, Sdt, nullptr, counts, rowlist, nullptr, nullptr, out);
    gemm3_k<EDIM, 3><<<dim3(64, 8), 512, 0, stream>>>(h2, nullptr, Wdt0, counts, rowlist, nullptr, nullptr, out);
  } else {
    // sequential fallback (round-4 proven ordering, h time-shared)
    gemm3_k<DIM, 0><<<dim3(32, 32), 512, 0, stream>>>(xb, Sgu, nullptr, counts, rowlist, h1, h1, nullptr);
    gemm3_k<EDIM, 2><<<dim3(32, 8), 512, 0, stream>>>(h1, Sdt, nullptr, counts, rowlist, nullptr, nullptr, out);
    gemm3_k<DIM, 1><<<dim3(64, 32), 512, 0, stream>>>(xb, nullptr, Wgu0, counts, rowlist, h1, h1, nullptr);
    gemm3_k<EDIM, 3><<<dim3(64, 8), 512, 0, stream>>>(h1, nullptr, Wdt0, counts, rowlist, nullptr, nullptr, out);
  }
}

// Round 9
// 278.980 us; speedup vs baseline: 1.0646x; 1.0646x over previous
//
#include <hip/hip_runtime.h>
#include <stdint.h>

#define NTOK 8192
#define DIM 1024
#define EDIM 2048

typedef __attribute__((ext_vector_type(8))) short bf16x8;
typedef __attribute__((ext_vector_type(4))) float f32x4;

__device__ __forceinline__ unsigned short f2bf(float f) {
  union { float f; unsigned u; } v; v.f = f;
  unsigned r = (v.u + 0x7FFF + ((v.u >> 16) & 1)) >> 16;
  return (unsigned short)r;
}

__device__ __forceinline__ unsigned pack2bf(float a, float b) {
  return (unsigned)f2bf(a) | ((unsigned)f2bf(b) << 16);
}

__device__ __forceinline__ void gload16(const void* g, void* l) {
  __builtin_amdgcn_global_load_lds(
      (const __attribute__((address_space(1))) unsigned int*)g,
      (__attribute__((address_space(3))) unsigned int*)l, 16, 0, 0);
}

// ---- mega preproc: blocks [0,1024) = x->bf16 + router logits;
// ---- blocks [1024, 1024+9*512) = 64x64 weight transpose/cast tiles ---------
__global__ void pre_k(const float* __restrict__ x, const float* __restrict__ Wr,
                      const float* __restrict__ bias,
                      const float* __restrict__ Sg, const float* __restrict__ Su,
                      const float* __restrict__ Sd, const float* __restrict__ Wg,
                      const float* __restrict__ Wu, const float* __restrict__ Wd,
                      unsigned short* __restrict__ xb, int* __restrict__ choice,
                      unsigned short* __restrict__ wt) {
  const int bx = blockIdx.x;
  const int t = threadIdx.x;
  const size_t MSZ = (size_t)DIM * EDIM;
  if (bx < 1024) {
    const int wid = t >> 6, lane = t & 63;
    const float b0 = bias[0], b1 = bias[1];
    const float2* wr = (const float2*)Wr;
    #pragma unroll
    for (int r = 0; r < 2; ++r) {
      const int n = bx * 8 + wid * 2 + r;
      const float4* xr = (const float4*)(x + (size_t)n * DIM);
      uint2* xo = (uint2*)(xb + (size_t)n * DIM);
      float s0 = 0.f, s1 = 0.f;
      #pragma unroll
      for (int i = 0; i < 4; ++i) {
        const int idx = i * 64 + lane;
        float4 v = xr[idx];
        float2 wa = wr[idx * 4], wb = wr[idx * 4 + 1], wc = wr[idx * 4 + 2], wd = wr[idx * 4 + 3];
        s0 += v.x * wa.x + v.y * wb.x + v.z * wc.x + v.w * wd.x;
        s1 += v.x * wa.y + v.y * wb.y + v.z * wc.y + v.w * wd.y;
        union { unsigned short s[4]; uint2 u; } o;
        o.s[0] = f2bf(v.x); o.s[1] = f2bf(v.y); o.s[2] = f2bf(v.z); o.s[3] = f2bf(v.w);
        xo[idx] = o.u;
      }
      #pragma unroll
      for (int off = 32; off; off >>= 1) {
        s0 += __shfl_xor(s0, off);
        s1 += __shfl_xor(s1, off);
      }
      if (lane == 0) choice[n] = (s1 + b1 > s0 + b0) ? 1 : 0;
    }
    return;
  }
  // ---- 64x64 transpose tiles; gate/up interleave 16-wide:
  // ---- f -> row (f>>4)*32 + (f&15) + type*16
  const int id = bx - 1024;
  const int mat = id >> 9;           // 512 tiles per matrix
  const int tile = id & 511;
  const float* src; unsigned short* dst; int type;
  switch (mat) {
    case 0: src = Sg;       dst = wt;            type = 0; break;
    case 1: src = Su;       dst = wt;            type = 1; break;
    case 2: src = Wg;       dst = wt + 4194304;  type = 0; break;
    case 3: src = Wu;       dst = wt + 4194304;  type = 1; break;
    case 4: src = Wg + MSZ; dst = wt + 8388608;  type = 0; break;
    case 5: src = Wu + MSZ; dst = wt + 8388608;  type = 1; break;
    case 6: src = Sd;       dst = wt + 12582912; type = 2; break;
    case 7: src = Wd;       dst = wt + 14680064; type = 2; break;
    default: src = Wd + MSZ; dst = wt + 16777216; type = 2; break;
  }
  const int C = (type == 2) ? DIM : EDIM;       // src cols (output N index)
  const int OSTR = (type == 2) ? EDIM : DIM;    // dst row stride
  __shared__ float ts[64][65];
  const int tC = C >> 6;
  const int r0 = (tile / tC) * 64, c0 = (tile % tC) * 64;
  {
    const int row4 = t >> 4, col4 = (t & 15) * 4;
    #pragma unroll
    for (int p = 0; p < 4; ++p) {
      const int row = p * 16 + row4;
      const float4 v = *(const float4*)&src[(size_t)(r0 + row) * C + c0 + col4];
      ts[row][col4 + 0] = v.x; ts[row][col4 + 1] = v.y;
      ts[row][col4 + 2] = v.z; ts[row][col4 + 3] = v.w;
    }
  }
  __syncthreads();
  {
    const int ch = t & 7;
    #pragma unroll
    for (int q = 0; q < 2; ++q) {
      const int fl = q * 32 + (t >> 3);
      float v0 = ts[ch * 8 + 0][fl], v1 = ts[ch * 8 + 1][fl];
      float v2 = ts[ch * 8 + 2][fl], v3 = ts[ch * 8 + 3][fl];
      float v4 = ts[ch * 8 + 4][fl], v5 = ts[ch * 8 + 5][fl];
      float v6 = ts[ch * 8 + 6][fl], v7 = ts[ch * 8 + 7][fl];
      uint4 o;
      o.x = pack2bf(v0, v1); o.y = pack2bf(v2, v3);
      o.z = pack2bf(v4, v5); o.w = pack2bf(v6, v7);
      const int f = c0 + fl;
      const int orow = (type == 2) ? f : (((f >> 4) << 5) + (f & 15) + (type << 4));
      *(uint4*)&dst[(size_t)orow * OSTR + r0 + ch * 8] = o;
    }
  }
}

// ---- single-block prefix scan -> compacted expert-sorted rowlist ------------
__global__ void scan_k(const int* __restrict__ choice, int* __restrict__ counts,
                       int* __restrict__ rowlist) {
  const int t = threadIdx.x;
  const int base = t * 8;
  int c[8]; int ones = 0;
  #pragma unroll
  for (int j = 0; j < 8; ++j) { c[j] = choice[base + j]; ones += c[j]; }
  const int lane = t & 63, wid = t >> 6;
  int v = ones;
  #pragma unroll
  for (int off = 1; off < 64; off <<= 1) {
    int o = __shfl_up(v, off);
    if (lane >= off) v += o;
  }
  __shared__ int wsum[16];
  if (lane == 63) wsum[wid] = v;
  __syncthreads();
  int pre = 0, tot = 0;
  #pragma unroll
  for (int w = 0; w < 16; ++w) {
    int s = wsum[w];
    if (w < wid) pre += s;
    tot += s;
  }
  const int excl = pre + v - ones;
  const int cnt0 = NTOK - tot;
  int p0 = base - excl;
  int p1 = cnt0 + excl;
  #pragma unroll
  for (int j = 0; j < 8; ++j) {
    if (c[j]) rowlist[p1++] = base + j;
    else rowlist[p0++] = base + j;
  }
  if (t == 0) { counts[0] = cnt0; counts[1] = tot; }
}

// ---- unified m97-style 128x128 MFMA GEMM, 256 thr, 32KB LDS, 4 blocks/CU ----
// MODE 0: up shared   (A=xb linear,  B=Bsh=Sgu,    h_s[pos] = silu(g)*u)
// MODE 1: up routed   (A=xb gather,  B=Brt+e*4M,   h_r[mstart+pos] = silu*u)
// MODE 2: down shared (A=h_s linear, B=Bsh=Sdt,    out[row] = )
// MODE 3: down routed (A=h_r compact,B=Brt+e*2M,   out[rl[row]] += scatter)
// MODE 4: merged up   (bx<64 -> shared job, else routed job; needs h_s != h_r)
template<int KDIM, int MODE>
__global__ __launch_bounds__(256, 4)
void gemm2_k(const unsigned short* __restrict__ A, const unsigned short* __restrict__ Bsh,
             const unsigned short* __restrict__ Brt, const int* __restrict__ counts,
             const int* __restrict__ rl, unsigned short* __restrict__ h_s,
             unsigned short* __restrict__ h_r, float* __restrict__ out) {
  constexpr int NT = KDIM / 64;
  constexpr int ROWB = KDIM * 2;

  int e = 0, mstart = 0, cntE = NTOK, r0;
  bool gat = false;
  const unsigned short* B;
  if (MODE == 4) {
    const int mt = blockIdx.x;
    if (mt < 64) { r0 = mt * 128; B = Bsh; }
    else {
      const int m2 = mt - 64;
      e = m2 >> 6;
      const int tile = m2 & 63;
      const int c0 = counts[0];
      cntE = e ? (NTOK - c0) : c0;
      mstart = e ? c0 : 0;
      r0 = tile * 128;
      if (r0 >= cntE) return;
      B = Brt + (size_t)e * 4194304u;
      gat = true;
    }
  } else if (MODE == 0) { r0 = blockIdx.x * 128; B = Bsh; }
  else if (MODE == 1) {
    e = blockIdx.x >> 6;
    const int mt = blockIdx.x & 63;
    const int c0 = counts[0];
    cntE = e ? (NTOK - c0) : c0;
    mstart = e ? c0 : 0;
    r0 = mt * 128;
    if (r0 >= cntE) return;
    B = Brt + (size_t)e * 4194304u;
    gat = true;
  } else if (MODE == 2) { r0 = blockIdx.x * 128; B = Bsh; }
  else {  // MODE 3
    e = blockIdx.x >> 6;
    const int mt = blockIdx.x & 63;
    const int c0 = counts[0];
    cntE = e ? (NTOK - c0) : c0;
    mstart = e ? c0 : 0;
    r0 = mt * 128;
    if (r0 >= cntE) return;
    B = Brt + (size_t)e * 2097152u;
  }
  const int n0 = blockIdx.y * 128;

  __shared__ __align__(16) unsigned char lA[16384];
  __shared__ __align__(16) unsigned char lB[16384];

  const int t = threadIdx.x;
  const int lane = t & 63;
  const int wm = t >> 7, wn = (t >> 6) & 1;
  const int l15 = lane & 15, l4 = lane >> 4;

  size_t aoff[4]; uint32_t boff[4]; int dsto[4];
  #pragma unroll
  for (int i = 0; i < 4; ++i) {
    const int flat = i * 4096 + t * 16;
    const int row = flat >> 7;
    const int kb = (flat & 127) ^ ((row & 7) << 4);
    int idx = r0 + row;
    int ar;
    if (MODE == 1 || MODE == 4) {
      if (gat) { if (idx >= cntE) idx = cntE - 1; ar = rl[mstart + idx]; }
      else ar = idx;
    } else if (MODE == 3) {
      if (idx >= cntE) idx = cntE - 1;
      ar = mstart + idx;
    } else ar = idx;
    aoff[i] = (size_t)ar * ROWB + kb;
    boff[i] = (uint32_t)(n0 + row) * ROWB + kb;
    dsto[i] = flat;
  }

  f32x4 acc[4][4];
  #pragma unroll
  for (int i = 0; i < 4; ++i)
    #pragma unroll
    for (int j = 0; j < 4; ++j) acc[i][j] = f32x4{0.f, 0.f, 0.f, 0.f};

  const char* Ab = (const char*)A;
  const char* Bb = (const char*)B;

  for (int kt = 0; kt < NT; ++kt) {
    __syncthreads();
    const size_t ko = (size_t)kt * 128;
    #pragma unroll
    for (int i = 0; i < 4; ++i) {
      gload16(Ab + aoff[i] + ko, lA + dsto[i]);
      gload16(Bb + boff[i] + ko, lB + dsto[i]);
    }
    __syncthreads();
    #pragma unroll
    for (int ks = 0; ks < 2; ++ks) {
      bf16x8 af[4], bf[4];
      const int kb = ks * 64 + (l4 << 4);
      #pragma unroll
      for (int mi = 0; mi < 4; ++mi) {
        const int row = wm * 64 + mi * 16 + l15;
        af[mi] = *(const bf16x8*)(lA + row * 128 + (kb ^ ((row & 7) << 4)));
      }
      #pragma unroll
      for (int ni = 0; ni < 4; ++ni) {
        const int col = wn * 64 + ni * 16 + l15;
        bf[ni] = *(const bf16x8*)(lB + col * 128 + (kb ^ ((col & 7) << 4)));
      }
      #pragma unroll
      for (int mi = 0; mi < 4; ++mi)
        #pragma unroll
        for (int ni = 0; ni < 4; ++ni)
          acc[mi][ni] = __builtin_amdgcn_mfma_f32_16x16x32_bf16(af[mi], bf[ni], acc[mi][ni], 0, 0, 0);
    }
  }

  // epilogue
  #pragma unroll
  for (int mi = 0; mi < 4; ++mi) {
    #pragma unroll
    for (int r = 0; r < 4; ++r) {
      const int rit = wm * 64 + mi * 16 + l4 * 4 + r;
      const int pos = r0 + rit;
      if (MODE == 0 || MODE == 1 || MODE == 4) {
        if (gat && pos >= cntE) continue;
        unsigned short* hr = (gat ? h_r : h_s) + (size_t)(mstart + pos) * EDIM;
        const int f0 = (n0 >> 1) + wn * 32;
        #pragma unroll
        for (int j = 0; j < 2; ++j) {
          const float g = acc[mi][2 * j][r], u = acc[mi][2 * j + 1][r];
          hr[f0 + j * 16 + l15] = f2bf(g / (1.f + __expf(-g)) * u);
        }
      } else if (MODE == 2) {
        float* orow = out + (size_t)pos * DIM;
        #pragma unroll
        for (int n = 0; n < 4; ++n)
          orow[n0 + wn * 64 + n * 16 + l15] = acc[mi][n][r];
      } else {
        if (pos >= cntE) continue;
        const int tok = rl[mstart + pos];
        float* orow = out + (size_t)tok * DIM;
        #pragma unroll
        for (int n = 0; n < 4; ++n)
          orow[n0 + wn * 64 + n * 16 + l15] += acc[mi][n][r];
      }
    }
  }
}

extern "C" void kernel_launch(void* const* d_in, const int* in_sizes, int n_in,
                              void* d_out, int out_size, void* d_ws, size_t ws_size,
                              hipStream_t stream) {
  const float* x  = (const float*)d_in[0];
  const float* Wr = (const float*)d_in[1];
  const float* rb = (const float*)d_in[2];
  const float* Wg = (const float*)d_in[3];
  const float* Wu = (const float*)d_in[4];
  const float* Wd = (const float*)d_in[5];
  const float* Sg = (const float*)d_in[6];
  const float* Su = (const float*)d_in[7];
  const float* Sd = (const float*)d_in[8];
  float* out = (float*)d_out;

  char* ws = (char*)d_ws;
  int* counts  = (int*)ws;                                 // 256 B
  int* choice  = (int*)(ws + 256);                         // 32 KiB
  int* rowlist = (int*)(ws + 256 + 32768);                 // 32 KiB
  unsigned short* xb = (unsigned short*)(ws + 256 + 65536);  // 16 MiB
  unsigned short* wt = xb + (size_t)NTOK * DIM;            // 36 MiB of weights
  unsigned short* h1 = wt + 18874368;                      // [8192][2048] bf16
  unsigned short* h2 = h1 + (size_t)NTOK * EDIM;           // second h (merged path)

  const unsigned short* Sgu  = wt;             // [4096][1024] gate/up interleaved
  const unsigned short* Wgu0 = wt + 4194304;   // 2 x [4096][1024]
  const unsigned short* Sdt  = wt + 12582912;  // [1024][2048]
  const unsigned short* Wdt0 = wt + 14680064;  // 2 x [1024][2048]

  pre_k<<<1024 + 9 * 512, 256, 0, stream>>>(x, Wr, rb, Sg, Su, Sd, Wg, Wu, Wd,
                                            xb, choice, wt);
  scan_k<<<1, 1024, 0, stream>>>(choice, counts, rowlist);

  const size_t needed = 256 + 65536 + 16777216ull + 37748736ull + 2 * 33554432ull;
  if (ws_size >= needed) {
    // merged ups (shared job: bx<64; routed job: bx in [64,192)) -> h1 / h2
    gemm2_k<DIM, 4><<<dim3(192, 32), 256, 0, stream>>>(xb, Sgu, Wgu0, counts, rowlist, h1, h2, nullptr);
    gemm2_k<EDIM, 2><<<dim3(64, 8), 256, 0, stream>>>(h1, Sdt, nullptr, counts, rowlist, nullptr, nullptr, out);
    gemm2_k<EDIM, 3><<<dim3(128, 8), 256, 0, stream>>>(h2, nullptr, Wdt0, counts, rowlist, nullptr, nullptr, out);
  } else {
    // sequential fallback (round-4 proven ordering, h time-shared)
    gemm2_k<DIM, 0><<<dim3(64, 32), 256, 0, stream>>>(xb, Sgu, nullptr, counts, rowlist, h1, h1, nullptr);
    gemm2_k<EDIM, 2><<<dim3(64, 8), 256, 0, stream>>>(h1, Sdt, nullptr, counts, rowlist, nullptr, nullptr, out);
    gemm2_k<DIM, 1><<<dim3(128, 32), 256, 0, stream>>>(xb, nullptr, Wgu0, counts, rowlist, h1, h1, nullptr);
    gemm2_k<EDIM, 3><<<dim3(128, 8), 256, 0, stream>>>(h1, nullptr, Wdt0, counts, rowlist, nullptr, nullptr, out);
  }
}